// Round 1
// baseline (70.804 us; speedup 1.0000x reference)
//
#include <hip/hip_runtime.h>
#include <math.h>

#define BLOCK 128

namespace {
constexpr int Hh = 64;
constexpr int Ww = 64;
constexpr int NPIX = Hh * Ww;                                     // 4096
constexpr int NBATCH = 8;
constexpr int NOFF = (2 * Hh - 1) * (2 * Ww - 1);                 // 16129
constexpr int D2MAX = (Hh - 1) * (Hh - 1) + (Ww - 1) * (Ww - 1);  // 7938
constexpr int CHUNKS = NPIX / BLOCK;                              // 32

struct OffTable { unsigned int v[NOFF]; };

// Counting sort of all (dy,dx) offsets by d2 = dy^2+dx^2, at compile time.
// Intra-shell order is arbitrary — provably irrelevant (equal multiplier d2,
// truncation mass per shell is order-independent).
constexpr OffTable make_table() {
  OffTable t{};
  int pos[D2MAX + 1] = {};
  for (int dy = -(Hh - 1); dy <= (Hh - 1); ++dy)
    for (int dx = -(Ww - 1); dx <= (Ww - 1); ++dx)
      pos[dy * dy + dx * dx] += 1;
  int acc = 0;
  for (int d = 0; d <= D2MAX; ++d) { int c = pos[d]; pos[d] = acc; acc += c; }
  for (int dy = -(Hh - 1); dy <= (Hh - 1); ++dy)
    for (int dx = -(Ww - 1); dx <= (Ww - 1); ++dx) {
      int d2 = dy * dy + dx * dx;
      t.v[pos[d2]++] = ((unsigned)d2 << 14) | ((unsigned)(dy + (Hh - 1)) << 7) |
                       (unsigned)(dx + (Ww - 1));
    }
  return t;
}
}  // namespace

__device__ constexpr OffTable g_off = make_table();

__global__ __launch_bounds__(BLOCK) void dtm_kernel(const float* __restrict__ x,
                                                    float* __restrict__ out) {
  __shared__ __align__(16) float w[NPIX];      // one batch's 64x64 weights (16 KB)
  __shared__ float wavesum[BLOCK / 64];

  const int b = blockIdx.x / CHUNKS;
  const int chunk = blockIdx.x % CHUNKS;
  const int tid = threadIdx.x;

  // --- Stage batch image into LDS (float4, coalesced) + accumulate total mass.
  const float4* __restrict__ xb4 = (const float4*)(x + b * NPIX);
  float4* w4 = (float4*)w;
  float local = 0.f;
#pragma unroll
  for (int k = 0; k < NPIX / 4 / BLOCK; ++k) {
    float4 v = xb4[k * BLOCK + tid];
    w4[k * BLOCK + tid] = v;
    local += (v.x + v.y) + (v.z + v.w);
  }
  // wave butterfly reduce (width 64), then cross-wave via LDS
#pragma unroll
  for (int off = 32; off > 0; off >>= 1) local += __shfl_xor(local, off);
  if ((tid & 63) == 0) wavesum[tid >> 6] = local;
  __syncthreads();
  float total = 0.f;
#pragma unroll
  for (int i = 0; i < BLOCK / 64; ++i) total += wavesum[i];
  const float T = 0.01f * total;  // M0 * total_mass

  // --- Walk offsets in increasing d2; per-element truncation rule matches
  //     the reference's clip(min(w, T - prev_cumsum), 0) exactly.
  const int pix = chunk * BLOCK + tid;
  const int py = pix >> 6;
  const int px = pix & 63;

  float cum = 0.f, wds = 0.f;
  for (int i = 0; i < NOFF; ++i) {
    const unsigned v = g_off.v[i];          // wave-uniform -> scalar load
    const int d2 = (int)(v >> 14);
    const int dy = (int)((v >> 7) & 127u) - (Hh - 1);
    const int dx = (int)(v & 127u) - (Ww - 1);
    const int ny = py + dy;
    const int nx = px + dx;
    if ((unsigned)ny < (unsigned)Hh && (unsigned)nx < (unsigned)Ww) {
      const float wv = w[ny * Ww + nx];
      float rem = T - cum;
      rem = rem > 0.f ? rem : 0.f;
      const float eff = wv < rem ? wv : rem;
      wds = fmaf(eff, (float)d2, wds);
      cum += wv;
    }
    if (__all(cum >= T)) break;             // wave-wide early exit
  }

  const float res = (T > 0.f) ? sqrtf(wds / T) : 0.f;
  out[b * NPIX + pix] = res;
}

extern "C" void kernel_launch(void* const* d_in, const int* in_sizes, int n_in,
                              void* d_out, int out_size, void* d_ws, size_t ws_size,
                              hipStream_t stream) {
  (void)in_sizes; (void)n_in; (void)out_size; (void)d_ws; (void)ws_size;
  const float* x = (const float*)d_in[0];
  float* out = (float*)d_out;
  dtm_kernel<<<dim3(NBATCH * CHUNKS), dim3(BLOCK), 0, stream>>>(x, out);
}

// Round 2
// 59.081 us; speedup vs baseline: 1.1984x; 1.1984x over previous
//
#include <hip/hip_runtime.h>
#include <math.h>

#define BLOCK 128
#define U 8

namespace {
constexpr int Hh = 64, Ww = 64;
constexpr int NPIX = Hh * Ww;                 // 4096
constexpr int NBATCH = 8;
constexpr int NOFF = 127 * 127;               // 16129
constexpr int D2MAX = 2 * 63 * 63;            // 7938
constexpr int CHUNKS = NPIX / BLOCK;          // 32 blocks per batch, 2 rows each
constexpr int LW = 192;                       // 64-col zero halo on each side
constexpr int LDSN = 64 * LW;                 // 12288 floats = 48 KB
constexpr int NMAIN = ((NOFF + 2 * U - 1) / (2 * U)) * (2 * U);  // 16144
constexpr int NOFFP = NMAIN + 2 * U;          // 16160 (covers deepest speculative TLOAD)

struct Tab {
  float d2f[NOFFP];
  int rel[NOFFP];
};

// Compile-time counting sort of all (dy,dx) by d2. Intra-shell order is
// irrelevant (equal d2 multiplier => truncated mass per shell is order-free).
// rel = dy*LW+dx pre-bakes the LDS address delta. Pad entries have rel forced
// far out-of-range -> validity test fails -> contribution exactly 0.
constexpr Tab make_table() {
  Tab t{};
  int pos[D2MAX + 1] = {};
  for (int dy = -63; dy <= 63; ++dy)
    for (int dx = -63; dx <= 63; ++dx) pos[dy * dy + dx * dx] += 1;
  int acc = 0;
  for (int d = 0; d <= D2MAX; ++d) { int c = pos[d]; pos[d] = acc; acc += c; }
  for (int dy = -63; dy <= 63; ++dy)
    for (int dx = -63; dx <= 63; ++dx) {
      const int d2 = dy * dy + dx * dx;
      const int p = pos[d2]++;
      t.d2f[p] = (float)d2;
      t.rel[p] = dy * LW + dx;
    }
  for (int p = NOFF; p < NOFFP; ++p) { t.d2f[p] = 0.f; t.rel[p] = 4 * LDSN; }
  return t;
}
}  // namespace

__device__ constexpr Tab g_tab = make_table();

__global__ __launch_bounds__(BLOCK) void dtm_kernel(const float* __restrict__ x,
                                                    float* __restrict__ out) {
  __shared__ __align__(16) float w[LDSN];
  __shared__ float wavesum[BLOCK / 64];

  const int b = blockIdx.x / CHUNKS;
  const int chunk = blockIdx.x % CHUNKS;
  const int tid = threadIdx.x;

  // --- zero-fill LDS (center + halos), float4
  float4* w4 = (float4*)w;
#pragma unroll
  for (int k = 0; k < LDSN / 4 / BLOCK; ++k)  // 24
    w4[k * BLOCK + tid] = float4{0.f, 0.f, 0.f, 0.f};
  __syncthreads();

  // --- stage batch image into LDS center (coalesced float4) + total mass
  const float4* __restrict__ xb4 = (const float4*)(x + b * NPIX);
  float local = 0.f;
#pragma unroll
  for (int k = 0; k < NPIX / 4 / BLOCK; ++k) {  // 8
    const int p4 = k * BLOCK + tid;
    const float4 v = xb4[p4];
    const int row = p4 >> 4;          // 16 float4 per image row
    const int col = (p4 & 15) << 2;
    *(float4*)&w[row * LW + 64 + col] = v;  // (64+col)*4 is 16B-aligned
    local += (v.x + v.y) + (v.z + v.w);
  }
#pragma unroll
  for (int off = 32; off; off >>= 1) local += __shfl_xor(local, off);
  if ((tid & 63) == 0) wavesum[tid >> 6] = local;
  __syncthreads();
  const float T = 0.01f * (wavesum[0] + wavesum[1]);  // M0 * total_mass

  // --- walk offsets in d2 order; addr = base + rel; row-valid <=> addr in range
  const int pix = chunk * BLOCK + tid;
  const int base = (pix >> 6) * LW + (pix & 63) + 64;

  float cum = 0.f, wds = 0.f;
  int relA[U], relB[U];
  float d2A[U], d2B[U], wvA[U], wvB[U];

#define TLOAD(BASE, REL, D2)                \
  _Pragma("unroll") for (int u = 0; u < U; ++u) { \
    REL[u] = g_tab.rel[(BASE) + u];         \
    D2[u] = g_tab.d2f[(BASE) + u];          \
  }

#define WLOAD(REL, WV)                                                  \
  _Pragma("unroll") for (int u = 0; u < U; ++u) {                       \
    const int addr = base + REL[u];                                     \
    const unsigned ac = min((unsigned)addr, (unsigned)(LDSN - 1));      \
    const float val = w[ac];                                            \
    WV[u] = ((unsigned)addr < (unsigned)LDSN) ? val : 0.f;              \
  }

#define ACC(WV, D2)                                \
  _Pragma("unroll") for (int u = 0; u < U; ++u) {  \
    float rem = T - cum;                           \
    rem = rem > 0.f ? rem : 0.f;                   \
    const float eff = WV[u] < rem ? WV[u] : rem;   \
    wds = fmaf(eff, D2[u], wds);                   \
    cum += WV[u];                                  \
  }

  // software pipeline, depth 2: A/B ping-pong, 2 groups per body
  TLOAD(0, relA, d2A);
  WLOAD(relA, wvA);
  TLOAD(U, relB, d2B);

  for (int i = 0; i < NMAIN; i += 2 * U) {
    WLOAD(relB, wvB);                // group g+1 ds_reads (independent, issue early)
    ACC(wvA, d2A);                   // group g  (overlaps load latencies)
    if (__all(cum >= T)) break;
    TLOAD(i + 2 * U, relA, d2A);     // group g+2 table (wave-uniform -> SGPRs)
    ACC(wvB, d2B);                   // group g+1
    if (__all(cum >= T)) break;
    WLOAD(relA, wvA);                // group g+2 ds_reads
    TLOAD(i + 3 * U, relB, d2B);     // group g+3 table
  }
#undef TLOAD
#undef WLOAD
#undef ACC

  const float res = (T > 0.f) ? sqrtf(wds / T) : 0.f;
  out[b * NPIX + pix] = res;
}

extern "C" void kernel_launch(void* const* d_in, const int* in_sizes, int n_in,
                              void* d_out, int out_size, void* d_ws, size_t ws_size,
                              hipStream_t stream) {
  (void)in_sizes; (void)n_in; (void)out_size; (void)d_ws; (void)ws_size;
  const float* x = (const float*)d_in[0];
  float* out = (float*)d_out;
  dtm_kernel<<<dim3(NBATCH * CHUNKS), dim3(BLOCK), 0, stream>>>(x, out);
}

// Round 3
// 58.319 us; speedup vs baseline: 1.2141x; 1.0131x over previous
//
#include <hip/hip_runtime.h>
#include <math.h>

#define BLOCK 128
#define U 8

namespace {
constexpr int NPIX = 4096;                    // 64x64
constexpr int NBATCH = 8;
constexpr int NOFF = 127 * 127;               // 16129
constexpr int D2MAX = 2 * 63 * 63;            // 7938
constexpr int CHUNKS = NPIX / BLOCK;          // 32 blocks/batch, 2 rows each
constexpr int LW = 192;                       // 64-col zero halo each side
constexpr int LDSN = 64 * LW;                 // 12288 floats = 48 KB
constexpr int NMAIN = ((NOFF + 2 * U - 1) / (2 * U)) * (2 * U);  // 16144
constexpr int NOFFP = NMAIN + 2 * U;          // covers deepest speculative TLOAD

struct Tab {
  float d2f[NOFFP];
  int rel[NOFFP];
};

// Compile-time counting sort of all (dy,dx) by d2 = dy^2+dx^2. Intra-shell
// order is irrelevant (equal d2 multiplier -> truncated shell mass is
// order-free). rel = dy*LW+dx pre-bakes the LDS address delta. Pad entries
// have rel forced out-of-range -> they read the w[LDSN-1] halo zero.
constexpr Tab make_table() {
  Tab t{};
  int pos[D2MAX + 1] = {};
  for (int dy = -63; dy <= 63; ++dy)
    for (int dx = -63; dx <= 63; ++dx) pos[dy * dy + dx * dx] += 1;
  int acc = 0;
  for (int d = 0; d <= D2MAX; ++d) { int c = pos[d]; pos[d] = acc; acc += c; }
  for (int dy = -63; dy <= 63; ++dy)
    for (int dx = -63; dx <= 63; ++dx) {
      const int d2 = dy * dy + dx * dx;
      const int p = pos[d2]++;
      t.d2f[p] = (float)d2;
      t.rel[p] = dy * LW + dx;
    }
  for (int p = NOFF; p < NOFFP; ++p) { t.d2f[p] = 0.f; t.rel[p] = 4 * LDSN; }
  return t;
}
}  // namespace

__device__ constexpr Tab g_tab = make_table();

__global__ __launch_bounds__(BLOCK) void dtm_kernel(const float* __restrict__ x,
                                                    float* __restrict__ out) {
  __shared__ __align__(16) float w[LDSN];
  __shared__ float wavesum[2];

  const int b = blockIdx.x / CHUNKS;
  const int chunk = blockIdx.x % CHUNKS;
  const int tid = threadIdx.x;

  // --- zero only the halos (cols [0,64) and [128,192) of each row);
  //     disjoint from the staged center, so no barrier needed in between.
  float4* w4 = (float4*)w;
#pragma unroll
  for (int k = 0; k < 16; ++k) {
    const int h = k * BLOCK + tid;  // 0..2047 halo-float4 id
    const int row = h >> 5;         // 32 halo float4s per row
    const int c = h & 31;
    w4[row * 48 + (c < 16 ? c : c + 16)] = float4{0.f, 0.f, 0.f, 0.f};
  }

  // --- stage batch image into LDS center (coalesced float4) + total mass
  const float4* __restrict__ xb4 = (const float4*)(x + b * NPIX);
  float local = 0.f;
#pragma unroll
  for (int k = 0; k < NPIX / 4 / BLOCK; ++k) {  // 8
    const int p4 = k * BLOCK + tid;
    const float4 v = xb4[p4];
    const int row = p4 >> 4;       // 16 float4 per image row
    const int col = (p4 & 15) << 2;
    *(float4*)&w[row * LW + 64 + col] = v;
    local += (v.x + v.y) + (v.z + v.w);
  }
#pragma unroll
  for (int off = 32; off; off >>= 1) local += __shfl_xor(local, off);
  if ((tid & 63) == 0) wavesum[tid >> 6] = local;
  __syncthreads();  // orders halo zeros + center stage + wavesum for all reads
  const float T = 0.01f * (wavesum[0] + wavesum[1]);  // M0 * total_mass

  // --- walk offsets in d2 order. Invalid addresses (row out of range, pad
  //     entries) all collapse via unsigned min onto w[LDSN-1], a halo zero —
  //     value-exact, no compare/select needed.
  const int pix = chunk * BLOCK + tid;
  const int base = (pix >> 6) * LW + (pix & 63) + 64;

  float cum = 0.f, wds = 0.f;
  int relA[U], relB[U];
  float d2A[U], d2B[U], wvA[U], wvB[U];

#define TLOAD(BASE, REL, D2)                       \
  _Pragma("unroll") for (int u = 0; u < U; ++u) {  \
    REL[u] = g_tab.rel[(BASE) + u];                \
    D2[u] = g_tab.d2f[(BASE) + u];                 \
  }

#define WLOAD(REL, WV)                                                     \
  _Pragma("unroll") for (int u = 0; u < U; ++u) {                          \
    WV[u] = w[min((unsigned)(base + REL[u]), (unsigned)(LDSN - 1))];       \
  }

#define ACC(WV, D2)                                \
  _Pragma("unroll") for (int u = 0; u < U; ++u) {  \
    float rem = T - cum;                           \
    rem = rem > 0.f ? rem : 0.f;                   \
    const float eff = WV[u] < rem ? WV[u] : rem;   \
    wds = fmaf(eff, D2[u], wds);                   \
    cum += WV[u];                                  \
  }

  // depth-2 software pipeline, A/B ping-pong, 2 groups of U per body
  TLOAD(0, relA, d2A);
  WLOAD(relA, wvA);
  TLOAD(U, relB, d2B);

  for (int i = 0; i < NMAIN; i += 2 * U) {
    WLOAD(relB, wvB);                // group g+1 ds_reads (independent)
    ACC(wvA, d2A);                   // group g (covers load latency)
    if (__all(cum >= T)) break;
    TLOAD(i + 2 * U, relA, d2A);     // group g+2 table (wave-uniform -> SGPR)
    ACC(wvB, d2B);                   // group g+1
    if (__all(cum >= T)) break;
    WLOAD(relA, wvA);                // group g+2 ds_reads
    TLOAD(i + 3 * U, relB, d2B);     // group g+3 table
  }
#undef TLOAD
#undef WLOAD
#undef ACC

  const float res = (T > 0.f) ? sqrtf(wds / T) : 0.f;
  out[b * NPIX + pix] = res;
}

extern "C" void kernel_launch(void* const* d_in, const int* in_sizes, int n_in,
                              void* d_out, int out_size, void* d_ws, size_t ws_size,
                              hipStream_t stream) {
  (void)in_sizes; (void)n_in; (void)out_size; (void)d_ws; (void)ws_size;
  const float* x = (const float*)d_in[0];
  float* out = (float*)d_out;
  dtm_kernel<<<dim3(NBATCH * CHUNKS), dim3(BLOCK), 0, stream>>>(x, out);
}